// Round 4
// baseline (507.543 us; speedup 1.0000x reference)
//
#include <hip/hip_runtime.h>
#include <stdint.h>

#define DEVI __device__ __forceinline__

typedef __attribute__((ext_vector_type(8))) short short8;
typedef __attribute__((ext_vector_type(4))) float f32x4;
typedef __attribute__((ext_vector_type(4))) unsigned int u32x4;

static constexpr int Bn = 2;
static constexpr int Tn = 2048;
static constexpr int Cn = 2048;
static constexpr int NH = 16;
static constexpr int HD = 128;
static constexpr int Kdim = 2048;

DEVI unsigned short f2bf(float f) {
  union { float f; unsigned u; } v; v.f = f;
  return (unsigned short)((v.u + 0x7FFFu + ((v.u >> 16) & 1u)) >> 16);
}

DEVI void gload_lds16(const void* g, void* l) {
  __builtin_amdgcn_global_load_lds(
      (const __attribute__((address_space(1))) void*)g,
      (__attribute__((address_space(3))) void*)l, 16, 0, 0);
}

// ---------------- cast fp32 -> bf16 (RNE) ----------------
__global__ __launch_bounds__(256) void cast_bf16_kernel(
    const float* __restrict__ src, unsigned short* __restrict__ dst, int n) {
  int idx = (blockIdx.x * blockDim.x + threadIdx.x) * 4;
  const int stride = gridDim.x * blockDim.x * 4;
  for (; idx < n; idx += stride) {
    f32x4 f = *(const f32x4*)(src + idx);
    unsigned short o[4];
    o[0] = f2bf(f[0]); o[1] = f2bf(f[1]); o[2] = f2bf(f[2]); o[3] = f2bf(f[3]);
    *(unsigned long long*)(dst + idx) = *(const unsigned long long*)o;
  }
}

// one dispatch for all 4 weight matrices (blockIdx.y selects)
__global__ __launch_bounds__(256) void cast4_kernel(
    const float* __restrict__ s0, const float* __restrict__ s1,
    const float* __restrict__ s2, const float* __restrict__ s3,
    unsigned short* __restrict__ d0, unsigned short* __restrict__ d1,
    unsigned short* __restrict__ d2, unsigned short* __restrict__ d3, int n) {
  const int w = blockIdx.y;
  const float* src = (w == 0) ? s0 : (w == 1) ? s1 : (w == 2) ? s2 : s3;
  unsigned short* dst = (w == 0) ? d0 : (w == 1) ? d1 : (w == 2) ? d2 : d3;
  int idx = (blockIdx.x * blockDim.x + threadIdx.x) * 4;
  const int stride = gridDim.x * blockDim.x * 4;
  for (; idx < n; idx += stride) {
    f32x4 f = *(const f32x4*)(src + idx);
    unsigned short o[4];
    o[0] = f2bf(f[0]); o[1] = f2bf(f[1]); o[2] = f2bf(f[2]); o[3] = f2bf(f[3]);
    *(unsigned long long*)(dst + idx) = *(const unsigned long long*)o;
  }
}

// ---------------- fused QKV projection GEMM ----------------
// 1536 blocks, XCD-swizzled: xcd = bid&7 owns n-panels [6*xcd, 6*xcd+6),
// m-fastest so 32 consecutive same-XCD blocks share one B-panel (L2-hot).
// BK=64, XOR-swizzled LDS (slot = chunk ^ (row&7)) for conflict-free frags.
// Q/K out: (B,H,T,D) bf16 scattered; V out: (B,H,D,T) bf16 (pre-transposed).
__global__ __launch_bounds__(256) void gemm_qkv_fused_kernel(
    const unsigned short* __restrict__ X,
    const unsigned short* __restrict__ Wq_, const unsigned short* __restrict__ Wk_,
    const unsigned short* __restrict__ Wv_,
    const float* __restrict__ bq_, const float* __restrict__ bk_, const float* __restrict__ bv_,
    unsigned short* __restrict__ Qo, unsigned short* __restrict__ Ko,
    unsigned short* __restrict__ Vo) {
  __shared__ unsigned short As[128 * 64];
  __shared__ unsigned short Bs[128 * 64];
  const int tid = threadIdx.x;
  const int wave = tid >> 6, lane = tid & 63;
  const int wm = wave >> 1, wn = wave & 1;
  const int quad = lane >> 4, lr = lane & 15;

  const int bid = blockIdx.x;
  const int xcd = bid & 7, local = bid >> 3;      // 192 blocks per xcd
  const int nidx = xcd * 6 + (local >> 5);        // 0..47
  const int m0 = (local & 31) * 128;
  const int sel = nidx >> 4;
  const int n0 = (nidx & 15) * 128;
  const unsigned short* W = (sel == 0) ? Wq_ : (sel == 1) ? Wk_ : Wv_;
  const float* bias = (sel == 0) ? bq_ : (sel == 1) ? bk_ : bv_;

  f32x4 acc[4][4];
  const f32x4 zero4 = {0.f, 0.f, 0.f, 0.f};
#pragma unroll
  for (int i = 0; i < 4; ++i)
#pragma unroll
    for (int j = 0; j < 4; ++j) acc[i][j] = zero4;

  const int srow = tid >> 3;                       // 0..31
  const int gq = (tid & 7) ^ (srow & 7);           // xor-swizzled global chunk
  const unsigned short* Ag = X + (size_t)(m0 + srow) * Kdim + gq * 8;
  const unsigned short* Bg = W + (size_t)(n0 + srow) * Kdim + gq * 8;
  unsigned short* Al = &As[tid * 8];
  unsigned short* Bl = &Bs[tid * 8];

  for (int k0 = 0; k0 < Kdim; k0 += 64) {
#pragma unroll
    for (int p = 0; p < 4; ++p) {
      gload_lds16(Ag + k0 + p * 32 * Kdim, Al + p * 2048);
      gload_lds16(Bg + k0 + p * 32 * Kdim, Bl + p * 2048);
    }
    __syncthreads();
#pragma unroll
    for (int ks2 = 0; ks2 < 2; ++ks2) {
      const int swz = (((ks2 << 2) | quad) ^ (lr & 7)) * 8;
      short8 af[4], bf[4];
#pragma unroll
      for (int mi = 0; mi < 4; ++mi)
        af[mi] = *(const short8*)&As[(wm * 64 + mi * 16 + lr) * 64 + swz];
#pragma unroll
      for (int ni = 0; ni < 4; ++ni)
        bf[ni] = *(const short8*)&Bs[(wn * 64 + ni * 16 + lr) * 64 + swz];
#pragma unroll
      for (int mi = 0; mi < 4; ++mi)
#pragma unroll
        for (int ni = 0; ni < 4; ++ni)
          acc[mi][ni] = __builtin_amdgcn_mfma_f32_16x16x32_bf16(af[mi], bf[ni], acc[mi][ni], 0, 0, 0);
    }
    __syncthreads();
  }

  if (sel == 2) {
    // V^T: out[(b,h,d,t)]; 4 consecutive m (=t) per acc reg quad -> 8B stores
#pragma unroll
    for (int ni = 0; ni < 4; ++ni) {
      const int n = n0 + wn * 64 + ni * 16 + lr;
      const float bv = bias[n];
      const int h = n >> 7, d = n & 127;
#pragma unroll
      for (int mi = 0; mi < 4; ++mi) {
        const int m = m0 + wm * 64 + mi * 16 + quad * 4;
        const int b = m >> 11, t = m & 2047;
        unsigned short o4[4];
#pragma unroll
        for (int r = 0; r < 4; ++r) o4[r] = f2bf(acc[mi][ni][r] + bv);
        *(unsigned long long*)&Vo[(((size_t)(b * NH + h)) * HD + d) * Tn + t] =
            *(const unsigned long long*)o4;
      }
    }
  } else {
    unsigned short* Out = (sel == 0) ? Qo : Ko;
#pragma unroll
    for (int ni = 0; ni < 4; ++ni) {
      const int n = n0 + wn * 64 + ni * 16 + lr;
      const float bv = bias[n];
      const int h = n >> 7, d = n & 127;
#pragma unroll
      for (int mi = 0; mi < 4; ++mi) {
#pragma unroll
        for (int r = 0; r < 4; ++r) {
          const int m = m0 + wm * 64 + mi * 16 + quad * 4 + r;
          const int b = m >> 11, t = m & 2047;
          Out[(((size_t)(b * NH + h)) * Tn + t) * HD + d] = f2bf(acc[mi][ni][r] + bv);
        }
      }
    }
  }
}

// ---------------- output projection GEMM (fp32 out) ----------------
// 512 blocks XCD-swizzled; same BK=64 xor-swizzle structure.
__global__ __launch_bounds__(256) void gemm_proj_kernel(
    const unsigned short* __restrict__ Aall,  // (B, 2048, 2048) = O^T rows (h*128+d), cols t
    const unsigned short* __restrict__ W,     // Wp (N=C, K) bf16
    const float* __restrict__ bias,
    float* __restrict__ Y) {                  // (B, T, C) fp32
  __shared__ unsigned short As[128 * 64];
  __shared__ unsigned short Bs[128 * 64];
  const int tid = threadIdx.x;
  const int wave = tid >> 6, lane = tid & 63;
  const int wm = wave >> 1, wn = wave & 1;
  const int quad = lane >> 4, lr = lane & 15;

  const int bid = blockIdx.x;
  const int xcd = bid & 7, local = bid >> 3;   // 64 per xcd
  const int nidx = xcd * 2 + (local >> 5);     // 0..15
  const int rem = local & 31;
  const int bz = rem >> 4;
  const int m0 = (rem & 15) * 128, n0 = nidx * 128;
  const unsigned short* A = Aall + (size_t)bz * Cn * Tn;

  f32x4 acc[4][4];
  const f32x4 zero4 = {0.f, 0.f, 0.f, 0.f};
#pragma unroll
  for (int i = 0; i < 4; ++i)
#pragma unroll
    for (int j = 0; j < 4; ++j) acc[i][j] = zero4;

  const int srow = tid >> 3;
  const int gq = (tid & 7) ^ (srow & 7);
  const unsigned short* Ag = A + (size_t)(m0 + srow) * Kdim + gq * 8;
  const unsigned short* Bg = W + (size_t)(n0 + srow) * Kdim + gq * 8;
  unsigned short* Al = &As[tid * 8];
  unsigned short* Bl = &Bs[tid * 8];

  for (int k0 = 0; k0 < Kdim; k0 += 64) {
#pragma unroll
    for (int p = 0; p < 4; ++p) {
      gload_lds16(Ag + k0 + p * 32 * Kdim, Al + p * 2048);
      gload_lds16(Bg + k0 + p * 32 * Kdim, Bl + p * 2048);
    }
    __syncthreads();
#pragma unroll
    for (int ks2 = 0; ks2 < 2; ++ks2) {
      const int swz = (((ks2 << 2) | quad) ^ (lr & 7)) * 8;
      short8 af[4], bf[4];
#pragma unroll
      for (int mi = 0; mi < 4; ++mi)
        af[mi] = *(const short8*)&As[(wm * 64 + mi * 16 + lr) * 64 + swz];
#pragma unroll
      for (int ni = 0; ni < 4; ++ni)
        bf[ni] = *(const short8*)&Bs[(wn * 64 + ni * 16 + lr) * 64 + swz];
#pragma unroll
      for (int mi = 0; mi < 4; ++mi)
#pragma unroll
        for (int ni = 0; ni < 4; ++ni)
          acc[mi][ni] = __builtin_amdgcn_mfma_f32_16x16x32_bf16(af[mi], bf[ni], acc[mi][ni], 0, 0, 0);
    }
    __syncthreads();
  }

#pragma unroll
  for (int ni = 0; ni < 4; ++ni) {
    const int n = n0 + wn * 64 + ni * 16 + lr;
    const float bv = bias[n];
#pragma unroll
    for (int mi = 0; mi < 4; ++mi) {
#pragma unroll
      for (int r = 0; r < 4; ++r) {
        const int m = m0 + wm * 64 + mi * 16 + quad * 4 + r;
        Y[((size_t)bz * Tn + m) * Cn + n] = acc[mi][ni][r] + bv;
      }
    }
  }
}

// ---------------- flash attention (fixed-max softmax, paired q-tiles) ---
// Q,K: (BH, T, HD) bf16; V: (BH, HD, T) bf16 (written transposed by QKV).
// Output: O^T (B, H*HD, T) bf16 directly (epilogue transposes via Ps LDS).
__global__ __launch_bounds__(256, 1) void attn_kernel(
    const unsigned short* __restrict__ Q,
    const unsigned short* __restrict__ K,
    const unsigned short* __restrict__ V,
    unsigned short* __restrict__ Ot) {
  constexpr int KST = 136;
  constexpr int VST = 136;   // 144 x 136 (rows 128..143 = ones)
  constexpr int PST = 136;   // 128 x 136 (4 waves x 32 rows)
  __shared__ unsigned short Ks[128 * KST];
  __shared__ unsigned short Vs[144 * VST];
  __shared__ unsigned short Ps[128 * PST];

  const int tid = threadIdx.x;
  const int wave = tid >> 6, lane = tid & 63;
  const int quad = lane >> 4, lr = lane & 15;
  const int bh = blockIdx.y;
  const float SL = 0.08838834764831845f * 1.4426950408889634f;  // scale*log2(e)

  const unsigned short* Kp = K + (size_t)bh * Tn * HD;
  const unsigned short* Vp = V + (size_t)bh * HD * Tn;
  unsigned short* Pw = &Ps[wave * 32 * PST];

  for (int i = tid; i < 16 * VST; i += 256) Vs[128 * VST + i] = 0x3F80;

  const f32x4 zero4 = {0.f, 0.f, 0.f, 0.f};
#pragma unroll 1
  for (int half = 0; half < 2; ++half) {
    const int jt = half ? (15 - (int)blockIdx.x) : (int)blockIdx.x;
    const int q0 = jt * 128;

    const unsigned short* Qp = Q + ((size_t)bh * Tn + q0 + wave * 32) * HD;
    short8 qf[2][4];
#pragma unroll
    for (int mi = 0; mi < 2; ++mi)
#pragma unroll
      for (int ks = 0; ks < 4; ++ks)
        qf[mi][ks] = *(const short8*)&Qp[(mi * 16 + lr) * HD + ks * 32 + quad * 8];

    f32x4 oacc[2][9];
#pragma unroll
    for (int mi = 0; mi < 2; ++mi)
#pragma unroll
      for (int nd = 0; nd < 9; ++nd) oacc[mi][nd] = zero4;

    const int nch = q0 / 128 + 1;
    for (int c = 0; c < nch; ++c) {
      const int k0 = c * 128;
      {
        const int r = tid >> 1;
        const int cc = (tid & 1) * 64;
        const unsigned short* kg = &Kp[(size_t)(k0 + r) * HD + cc];
        const unsigned short* vg = &Vp[(size_t)r * Tn + k0 + cc];
        unsigned short* kl = &Ks[r * KST + cc];
        unsigned short* vl = &Vs[r * VST + cc];
#pragma unroll
        for (int p = 0; p < 8; ++p) {
          *(u32x4*)(kl + p * 8) = *(const u32x4*)(kg + p * 8);
          *(u32x4*)(vl + p * 8) = *(const u32x4*)(vg + p * 8);
        }
      }
      __syncthreads();

      f32x4 sa[2][8];
#pragma unroll
      for (int mi = 0; mi < 2; ++mi)
#pragma unroll
        for (int nt = 0; nt < 8; ++nt) sa[mi][nt] = zero4;
#pragma unroll
      for (int nt = 0; nt < 8; ++nt) {
        short8 kf[4];
#pragma unroll
        for (int ks = 0; ks < 4; ++ks)
          kf[ks] = *(const short8*)&Ks[(nt * 16 + lr) * KST + ks * 32 + quad * 8];
#pragma unroll
        for (int mi = 0; mi < 2; ++mi)
#pragma unroll
          for (int ks = 0; ks < 4; ++ks)
            sa[mi][nt] = __builtin_amdgcn_mfma_f32_16x16x32_bf16(qf[mi][ks], kf[ks], sa[mi][nt], 0, 0, 0);
      }

      if (k0 == q0) {
#pragma unroll
        for (int mi = 0; mi < 2; ++mi)
#pragma unroll
          for (int nt = 0; nt < 8; ++nt)
#pragma unroll
            for (int r = 0; r < 4; ++r) {
              const int qg = q0 + wave * 32 + mi * 16 + quad * 4 + r;
              const int kg = k0 + nt * 16 + lr;
              if (kg > qg) sa[mi][nt][r] = -3.0e38f;
            }
      }

#pragma unroll
      for (int mi = 0; mi < 2; ++mi)
#pragma unroll
        for (int nt = 0; nt < 8; ++nt)
#pragma unroll
          for (int r = 0; r < 4; ++r) {
            const float p = __builtin_amdgcn_exp2f(sa[mi][nt][r] * SL);
            Pw[(mi * 16 + quad * 4 + r) * PST + nt * 16 + lr] = f2bf(p);
          }

#pragma unroll
      for (int kt = 0; kt < 4; ++kt) {
        short8 pf[2];
#pragma unroll
        for (int mi = 0; mi < 2; ++mi)
          pf[mi] = *(const short8*)&Pw[(mi * 16 + lr) * PST + kt * 32 + quad * 8];
#pragma unroll
        for (int nd = 0; nd < 9; ++nd) {
          short8 vf = *(const short8*)&Vs[(nd * 16 + lr) * VST + kt * 32 + quad * 8];
#pragma unroll
          for (int mi = 0; mi < 2; ++mi)
            oacc[mi][nd] = __builtin_amdgcn_mfma_f32_16x16x32_bf16(pf[mi], vf, oacc[mi][nd], 0, 0, 0);
        }
      }
      __syncthreads();
    }

    // epilogue: normalize, stage into Ps (t-major), write O^T coalesced
#pragma unroll
    for (int mi = 0; mi < 2; ++mi)
#pragma unroll
      for (int r = 0; r < 4; ++r) {
        const float rl = 1.0f / oacc[mi][8][r];
        const int tl = wave * 32 + mi * 16 + quad * 4 + r;
#pragma unroll
        for (int nd = 0; nd < 8; ++nd)
          Ps[tl * PST + nd * 16 + lr] = f2bf(oacc[mi][nd][r] * rl);
      }
    __syncthreads();
    {
      unsigned short* Od = Ot + (size_t)bh * HD * Tn + q0;  // row = d, stride Tn
#pragma unroll
      for (int p = 0; p < 8; ++p) {
        const int d = p * 16 + (tid >> 4);
        const int t8 = (tid & 15) * 8;
        alignas(16) unsigned short v[8];
#pragma unroll
        for (int j = 0; j < 8; ++j) v[j] = Ps[(t8 + j) * PST + d];
        *(u32x4*)&Od[(size_t)d * Tn + t8] = *(const u32x4*)v;
      }
    }
    __syncthreads();
  }
}

extern "C" void kernel_launch(void* const* d_in, const int* in_sizes, int n_in,
                              void* d_out, int out_size, void* d_ws, size_t ws_size,
                              hipStream_t stream) {
  const float* x  = (const float*)d_in[0];
  const float* Wq = (const float*)d_in[1];
  const float* bq = (const float*)d_in[2];
  const float* Wk = (const float*)d_in[3];
  const float* bk = (const float*)d_in[4];
  const float* Wv = (const float*)d_in[5];
  const float* bv = (const float*)d_in[6];
  const float* Wp = (const float*)d_in[7];
  const float* bp = (const float*)d_in[8];
  float* out = (float*)d_out;

  char* ws = (char*)d_ws;
  const size_t MB = 1ull << 20;
  unsigned short* Xbf = (unsigned short*)(ws);             // 16MB
  unsigned short* Wqb = (unsigned short*)(ws + 16 * MB);   // 8MB each
  unsigned short* Wkb = (unsigned short*)(ws + 24 * MB);
  unsigned short* Wvb = (unsigned short*)(ws + 32 * MB);
  unsigned short* Wpb = (unsigned short*)(ws + 40 * MB);
  unsigned short* Qb  = (unsigned short*)(ws + 48 * MB);   // 16MB
  unsigned short* Kb  = (unsigned short*)(ws + 64 * MB);   // 16MB
  unsigned short* Vtb = (unsigned short*)(ws + 80 * MB);   // 16MB (B,H,D,T)
  unsigned short* Otb = (unsigned short*)(ws + 96 * MB);   // 16MB (B,H*D,T)

  cast_bf16_kernel<<<dim3(1024), dim3(256), 0, stream>>>(x, Xbf, Bn * Tn * Cn);
  cast4_kernel<<<dim3(512, 4), dim3(256), 0, stream>>>(
      Wq, Wk, Wv, Wp, Wqb, Wkb, Wvb, Wpb, Cn * Cn);

  gemm_qkv_fused_kernel<<<dim3(1536), dim3(256), 0, stream>>>(
      Xbf, Wqb, Wkb, Wvb, bq, bk, bv, Qb, Kb, Vtb);

  attn_kernel<<<dim3(8, Bn * NH), dim3(256), 0, stream>>>(Qb, Kb, Vtb, Otb);

  gemm_proj_kernel<<<dim3(512), dim3(256), 0, stream>>>(Otb, Wpb, bp, out);
}

// Round 5
// 491.475 us; speedup vs baseline: 1.0327x; 1.0327x over previous
//
#include <hip/hip_runtime.h>
#include <stdint.h>

#define DEVI __device__ __forceinline__

typedef __attribute__((ext_vector_type(8))) short short8;
typedef __attribute__((ext_vector_type(4))) float f32x4;
typedef __attribute__((ext_vector_type(4))) unsigned int u32x4;

static constexpr int Bn = 2;
static constexpr int Tn = 2048;
static constexpr int Cn = 2048;
static constexpr int NH = 16;
static constexpr int HD = 128;
static constexpr int Kdim = 2048;

DEVI unsigned short f2bf(float f) {
  union { float f; unsigned u; } v; v.f = f;
  return (unsigned short)((v.u + 0x7FFFu + ((v.u >> 16) & 1u)) >> 16);
}

DEVI void gload_lds16(const void* g, void* l) {
  __builtin_amdgcn_global_load_lds(
      (const __attribute__((address_space(1))) void*)g,
      (__attribute__((address_space(3))) void*)l, 16, 0, 0);
}

// ---------------- cast fp32 -> bf16 (RNE) ----------------
__global__ __launch_bounds__(256) void cast_bf16_kernel(
    const float* __restrict__ src, unsigned short* __restrict__ dst, int n) {
  int idx = (blockIdx.x * blockDim.x + threadIdx.x) * 4;
  const int stride = gridDim.x * blockDim.x * 4;
  for (; idx < n; idx += stride) {
    f32x4 f = *(const f32x4*)(src + idx);
    unsigned short o[4];
    o[0] = f2bf(f[0]); o[1] = f2bf(f[1]); o[2] = f2bf(f[2]); o[3] = f2bf(f[3]);
    *(unsigned long long*)(dst + idx) = *(const unsigned long long*)o;
  }
}

// one dispatch for all 4 weight matrices (blockIdx.y selects)
__global__ __launch_bounds__(256) void cast4_kernel(
    const float* __restrict__ s0, const float* __restrict__ s1,
    const float* __restrict__ s2, const float* __restrict__ s3,
    unsigned short* __restrict__ d0, unsigned short* __restrict__ d1,
    unsigned short* __restrict__ d2, unsigned short* __restrict__ d3, int n) {
  const int w = blockIdx.y;
  const float* src = (w == 0) ? s0 : (w == 1) ? s1 : (w == 2) ? s2 : s3;
  unsigned short* dst = (w == 0) ? d0 : (w == 1) ? d1 : (w == 2) ? d2 : d3;
  int idx = (blockIdx.x * blockDim.x + threadIdx.x) * 4;
  const int stride = gridDim.x * blockDim.x * 4;
  for (; idx < n; idx += stride) {
    f32x4 f = *(const f32x4*)(src + idx);
    unsigned short o[4];
    o[0] = f2bf(f[0]); o[1] = f2bf(f[1]); o[2] = f2bf(f[2]); o[3] = f2bf(f[3]);
    *(unsigned long long*)(dst + idx) = *(const unsigned long long*)o;
  }
}

// ---------------- fused QKV projection GEMM ----------------
// grid (48, 32), x = n-panel (fastest): consecutive blocks share one A
// m-panel; B streams via L2/L3 (round-3 measured 106 MB FETCH).
// BK=64, XOR-swizzled LDS (slot = chunk ^ (row&7)) -> zero bank conflicts.
// Q/K out: (B,H,T,D) bf16 scattered; V out: (B,H,D,T) bf16 (pre-transposed).
__global__ __launch_bounds__(256) void gemm_qkv_fused_kernel(
    const unsigned short* __restrict__ X,
    const unsigned short* __restrict__ Wq_, const unsigned short* __restrict__ Wk_,
    const unsigned short* __restrict__ Wv_,
    const float* __restrict__ bq_, const float* __restrict__ bk_, const float* __restrict__ bv_,
    unsigned short* __restrict__ Qo, unsigned short* __restrict__ Ko,
    unsigned short* __restrict__ Vo) {
  __shared__ unsigned short As[128 * 64];
  __shared__ unsigned short Bs[128 * 64];
  const int tid = threadIdx.x;
  const int wave = tid >> 6, lane = tid & 63;
  const int wm = wave >> 1, wn = wave & 1;
  const int quad = lane >> 4, lr = lane & 15;

  const int nidx = blockIdx.x;                 // 0..47
  const int m0 = blockIdx.y * 128;
  const int sel = nidx >> 4;
  const int n0 = (nidx & 15) * 128;
  const unsigned short* W = (sel == 0) ? Wq_ : (sel == 1) ? Wk_ : Wv_;
  const float* bias = (sel == 0) ? bq_ : (sel == 1) ? bk_ : bv_;

  f32x4 acc[4][4];
  const f32x4 zero4 = {0.f, 0.f, 0.f, 0.f};
#pragma unroll
  for (int i = 0; i < 4; ++i)
#pragma unroll
    for (int j = 0; j < 4; ++j) acc[i][j] = zero4;

  const int srow = tid >> 3;                       // 0..31
  const int gq = (tid & 7) ^ (srow & 7);           // xor-swizzled global chunk
  const unsigned short* Ag = X + (size_t)(m0 + srow) * Kdim + gq * 8;
  const unsigned short* Bg = W + (size_t)(n0 + srow) * Kdim + gq * 8;
  unsigned short* Al = &As[tid * 8];
  unsigned short* Bl = &Bs[tid * 8];

  for (int k0 = 0; k0 < Kdim; k0 += 64) {
#pragma unroll
    for (int p = 0; p < 4; ++p) {
      gload_lds16(Ag + k0 + p * 32 * Kdim, Al + p * 2048);
      gload_lds16(Bg + k0 + p * 32 * Kdim, Bl + p * 2048);
    }
    __syncthreads();
#pragma unroll
    for (int ks2 = 0; ks2 < 2; ++ks2) {
      const int swz = (((ks2 << 2) | quad) ^ (lr & 7)) * 8;
      short8 af[4], bf[4];
#pragma unroll
      for (int mi = 0; mi < 4; ++mi)
        af[mi] = *(const short8*)&As[(wm * 64 + mi * 16 + lr) * 64 + swz];
#pragma unroll
      for (int ni = 0; ni < 4; ++ni)
        bf[ni] = *(const short8*)&Bs[(wn * 64 + ni * 16 + lr) * 64 + swz];
#pragma unroll
      for (int mi = 0; mi < 4; ++mi)
#pragma unroll
        for (int ni = 0; ni < 4; ++ni)
          acc[mi][ni] = __builtin_amdgcn_mfma_f32_16x16x32_bf16(af[mi], bf[ni], acc[mi][ni], 0, 0, 0);
    }
    __syncthreads();
  }

  if (sel == 2) {
    // V^T: out[(b,h,d,t)]; 4 consecutive m (=t) per acc reg quad -> 8B stores
#pragma unroll
    for (int ni = 0; ni < 4; ++ni) {
      const int n = n0 + wn * 64 + ni * 16 + lr;
      const float bv = bias[n];
      const int h = n >> 7, d = n & 127;
#pragma unroll
      for (int mi = 0; mi < 4; ++mi) {
        const int m = m0 + wm * 64 + mi * 16 + quad * 4;
        const int b = m >> 11, t = m & 2047;
        unsigned short o4[4];
#pragma unroll
        for (int r = 0; r < 4; ++r) o4[r] = f2bf(acc[mi][ni][r] + bv);
        *(unsigned long long*)&Vo[(((size_t)(b * NH + h)) * HD + d) * Tn + t] =
            *(const unsigned long long*)o4;
      }
    }
  } else {
    unsigned short* Out = (sel == 0) ? Qo : Ko;
#pragma unroll
    for (int ni = 0; ni < 4; ++ni) {
      const int n = n0 + wn * 64 + ni * 16 + lr;
      const float bv = bias[n];
      const int h = n >> 7, d = n & 127;
#pragma unroll
      for (int mi = 0; mi < 4; ++mi) {
#pragma unroll
        for (int r = 0; r < 4; ++r) {
          const int m = m0 + wm * 64 + mi * 16 + quad * 4 + r;
          const int b = m >> 11, t = m & 2047;
          Out[(((size_t)(b * NH + h)) * Tn + t) * HD + d] = f2bf(acc[mi][ni][r] + bv);
        }
      }
    }
  }
}

// ---------------- output projection GEMM (fp32 out) ----------------
// grid (16, 16, 2): x = n (fastest), y = m, z = batch. BK=64 xor-swizzle.
__global__ __launch_bounds__(256) void gemm_proj_kernel(
    const unsigned short* __restrict__ Aall,  // (B, 2048, 2048) = O^T rows (h*128+d), cols t
    const unsigned short* __restrict__ W,     // Wp (N=C, K) bf16
    const float* __restrict__ bias,
    float* __restrict__ Y) {                  // (B, T, C) fp32
  __shared__ unsigned short As[128 * 64];
  __shared__ unsigned short Bs[128 * 64];
  const int tid = threadIdx.x;
  const int wave = tid >> 6, lane = tid & 63;
  const int wm = wave >> 1, wn = wave & 1;
  const int quad = lane >> 4, lr = lane & 15;

  const int m0 = blockIdx.y * 128, n0 = blockIdx.x * 128;
  const int bz = blockIdx.z;
  const unsigned short* A = Aall + (size_t)bz * Cn * Tn;

  f32x4 acc[4][4];
  const f32x4 zero4 = {0.f, 0.f, 0.f, 0.f};
#pragma unroll
  for (int i = 0; i < 4; ++i)
#pragma unroll
    for (int j = 0; j < 4; ++j) acc[i][j] = zero4;

  const int srow = tid >> 3;
  const int gq = (tid & 7) ^ (srow & 7);
  const unsigned short* Ag = A + (size_t)(m0 + srow) * Kdim + gq * 8;
  const unsigned short* Bg = W + (size_t)(n0 + srow) * Kdim + gq * 8;
  unsigned short* Al = &As[tid * 8];
  unsigned short* Bl = &Bs[tid * 8];

  for (int k0 = 0; k0 < Kdim; k0 += 64) {
#pragma unroll
    for (int p = 0; p < 4; ++p) {
      gload_lds16(Ag + k0 + p * 32 * Kdim, Al + p * 2048);
      gload_lds16(Bg + k0 + p * 32 * Kdim, Bl + p * 2048);
    }
    __syncthreads();
#pragma unroll
    for (int ks2 = 0; ks2 < 2; ++ks2) {
      const int swz = (((ks2 << 2) | quad) ^ (lr & 7)) * 8;
      short8 af[4], bf[4];
#pragma unroll
      for (int mi = 0; mi < 4; ++mi)
        af[mi] = *(const short8*)&As[(wm * 64 + mi * 16 + lr) * 64 + swz];
#pragma unroll
      for (int ni = 0; ni < 4; ++ni)
        bf[ni] = *(const short8*)&Bs[(wn * 64 + ni * 16 + lr) * 64 + swz];
#pragma unroll
      for (int mi = 0; mi < 4; ++mi)
#pragma unroll
        for (int ni = 0; ni < 4; ++ni)
          acc[mi][ni] = __builtin_amdgcn_mfma_f32_16x16x32_bf16(af[mi], bf[ni], acc[mi][ni], 0, 0, 0);
    }
    __syncthreads();
  }

#pragma unroll
  for (int ni = 0; ni < 4; ++ni) {
    const int n = n0 + wn * 64 + ni * 16 + lr;
    const float bv = bias[n];
#pragma unroll
    for (int mi = 0; mi < 4; ++mi) {
#pragma unroll
      for (int r = 0; r < 4; ++r) {
        const int m = m0 + wm * 64 + mi * 16 + quad * 4 + r;
        Y[((size_t)bz * Tn + m) * Cn + n] = acc[mi][ni][r] + bv;
      }
    }
  }
}

// ---------------- flash attention (fixed-max softmax, paired q-tiles) ---
// Q,K: (BH, T, HD) bf16; V: (BH, HD, T) bf16 (written transposed by QKV).
// Output: O^T (B, H*HD, T) bf16 directly (epilogue transposes via Ps LDS).
__global__ __launch_bounds__(256, 1) void attn_kernel(
    const unsigned short* __restrict__ Q,
    const unsigned short* __restrict__ K,
    const unsigned short* __restrict__ V,
    unsigned short* __restrict__ Ot) {
  constexpr int KST = 136;
  constexpr int VST = 136;   // 144 x 136 (rows 128..143 = ones)
  constexpr int PST = 136;   // 128 x 136 (4 waves x 32 rows)
  __shared__ unsigned short Ks[128 * KST];
  __shared__ unsigned short Vs[144 * VST];
  __shared__ unsigned short Ps[128 * PST];

  const int tid = threadIdx.x;
  const int wave = tid >> 6, lane = tid & 63;
  const int quad = lane >> 4, lr = lane & 15;
  const int bh = blockIdx.y;
  const float SL = 0.08838834764831845f * 1.4426950408889634f;  // scale*log2(e)

  const unsigned short* Kp = K + (size_t)bh * Tn * HD;
  const unsigned short* Vp = V + (size_t)bh * HD * Tn;
  unsigned short* Pw = &Ps[wave * 32 * PST];

  for (int i = tid; i < 16 * VST; i += 256) Vs[128 * VST + i] = 0x3F80;

  const f32x4 zero4 = {0.f, 0.f, 0.f, 0.f};
#pragma unroll 1
  for (int half = 0; half < 2; ++half) {
    const int jt = half ? (15 - (int)blockIdx.x) : (int)blockIdx.x;
    const int q0 = jt * 128;

    const unsigned short* Qp = Q + ((size_t)bh * Tn + q0 + wave * 32) * HD;
    short8 qf[2][4];
#pragma unroll
    for (int mi = 0; mi < 2; ++mi)
#pragma unroll
      for (int ks = 0; ks < 4; ++ks)
        qf[mi][ks] = *(const short8*)&Qp[(mi * 16 + lr) * HD + ks * 32 + quad * 8];

    f32x4 oacc[2][9];
#pragma unroll
    for (int mi = 0; mi < 2; ++mi)
#pragma unroll
      for (int nd = 0; nd < 9; ++nd) oacc[mi][nd] = zero4;

    const int nch = q0 / 128 + 1;
    for (int c = 0; c < nch; ++c) {
      const int k0 = c * 128;
      {
        const int r = tid >> 1;
        const int cc = (tid & 1) * 64;
        const unsigned short* kg = &Kp[(size_t)(k0 + r) * HD + cc];
        const unsigned short* vg = &Vp[(size_t)r * Tn + k0 + cc];
        unsigned short* kl = &Ks[r * KST + cc];
        unsigned short* vl = &Vs[r * VST + cc];
#pragma unroll
        for (int p = 0; p < 8; ++p) {
          *(u32x4*)(kl + p * 8) = *(const u32x4*)(kg + p * 8);
          *(u32x4*)(vl + p * 8) = *(const u32x4*)(vg + p * 8);
        }
      }
      __syncthreads();

      f32x4 sa[2][8];
#pragma unroll
      for (int mi = 0; mi < 2; ++mi)
#pragma unroll
        for (int nt = 0; nt < 8; ++nt) sa[mi][nt] = zero4;
#pragma unroll
      for (int nt = 0; nt < 8; ++nt) {
        short8 kf[4];
#pragma unroll
        for (int ks = 0; ks < 4; ++ks)
          kf[ks] = *(const short8*)&Ks[(nt * 16 + lr) * KST + ks * 32 + quad * 8];
#pragma unroll
        for (int mi = 0; mi < 2; ++mi)
#pragma unroll
          for (int ks = 0; ks < 4; ++ks)
            sa[mi][nt] = __builtin_amdgcn_mfma_f32_16x16x32_bf16(qf[mi][ks], kf[ks], sa[mi][nt], 0, 0, 0);
      }

      if (k0 == q0) {
#pragma unroll
        for (int mi = 0; mi < 2; ++mi)
#pragma unroll
          for (int nt = 0; nt < 8; ++nt)
#pragma unroll
            for (int r = 0; r < 4; ++r) {
              const int qg = q0 + wave * 32 + mi * 16 + quad * 4 + r;
              const int kg = k0 + nt * 16 + lr;
              if (kg > qg) sa[mi][nt][r] = -3.0e38f;
            }
      }

#pragma unroll
      for (int mi = 0; mi < 2; ++mi)
#pragma unroll
        for (int nt = 0; nt < 8; ++nt)
#pragma unroll
          for (int r = 0; r < 4; ++r) {
            const float p = __builtin_amdgcn_exp2f(sa[mi][nt][r] * SL);
            Pw[(mi * 16 + quad * 4 + r) * PST + nt * 16 + lr] = f2bf(p);
          }

#pragma unroll
      for (int kt = 0; kt < 4; ++kt) {
        short8 pf[2];
#pragma unroll
        for (int mi = 0; mi < 2; ++mi)
          pf[mi] = *(const short8*)&Pw[(mi * 16 + lr) * PST + kt * 32 + quad * 8];
#pragma unroll
        for (int nd = 0; nd < 9; ++nd) {
          short8 vf = *(const short8*)&Vs[(nd * 16 + lr) * VST + kt * 32 + quad * 8];
#pragma unroll
          for (int mi = 0; mi < 2; ++mi)
            oacc[mi][nd] = __builtin_amdgcn_mfma_f32_16x16x32_bf16(pf[mi], vf, oacc[mi][nd], 0, 0, 0);
        }
      }
      __syncthreads();
    }

    // epilogue: normalize, stage into Ps (t-major), write O^T coalesced
#pragma unroll
    for (int mi = 0; mi < 2; ++mi)
#pragma unroll
      for (int r = 0; r < 4; ++r) {
        const float rl = 1.0f / oacc[mi][8][r];
        const int tl = wave * 32 + mi * 16 + quad * 4 + r;
#pragma unroll
        for (int nd = 0; nd < 8; ++nd)
          Ps[tl * PST + nd * 16 + lr] = f2bf(oacc[mi][nd][r] * rl);
      }
    __syncthreads();
    {
      unsigned short* Od = Ot + (size_t)bh * HD * Tn + q0;  // row = d, stride Tn
#pragma unroll
      for (int p = 0; p < 8; ++p) {
        const int d = p * 16 + (tid >> 4);
        const int t8 = (tid & 15) * 8;
        alignas(16) unsigned short v[8];
#pragma unroll
        for (int j = 0; j < 8; ++j) v[j] = Ps[(t8 + j) * PST + d];
        *(u32x4*)&Od[(size_t)d * Tn + t8] = *(const u32x4*)v;
      }
    }
    __syncthreads();
  }
}

extern "C" void kernel_launch(void* const* d_in, const int* in_sizes, int n_in,
                              void* d_out, int out_size, void* d_ws, size_t ws_size,
                              hipStream_t stream) {
  const float* x  = (const float*)d_in[0];
  const float* Wq = (const float*)d_in[1];
  const float* bq = (const float*)d_in[2];
  const float* Wk = (const float*)d_in[3];
  const float* bk = (const float*)d_in[4];
  const float* Wv = (const float*)d_in[5];
  const float* bv = (const float*)d_in[6];
  const float* Wp = (const float*)d_in[7];
  const float* bp = (const float*)d_in[8];
  float* out = (float*)d_out;

  char* ws = (char*)d_ws;
  const size_t MB = 1ull << 20;
  unsigned short* Xbf = (unsigned short*)(ws);             // 16MB
  unsigned short* Wqb = (unsigned short*)(ws + 16 * MB);   // 8MB each
  unsigned short* Wkb = (unsigned short*)(ws + 24 * MB);
  unsigned short* Wvb = (unsigned short*)(ws + 32 * MB);
  unsigned short* Wpb = (unsigned short*)(ws + 40 * MB);
  unsigned short* Qb  = (unsigned short*)(ws + 48 * MB);   // 16MB
  unsigned short* Kb  = (unsigned short*)(ws + 64 * MB);   // 16MB
  unsigned short* Vtb = (unsigned short*)(ws + 80 * MB);   // 16MB (B,H,D,T)
  unsigned short* Otb = (unsigned short*)(ws + 96 * MB);   // 16MB (B,H*D,T)

  cast_bf16_kernel<<<dim3(1024), dim3(256), 0, stream>>>(x, Xbf, Bn * Tn * Cn);
  cast4_kernel<<<dim3(512, 4), dim3(256), 0, stream>>>(
      Wq, Wk, Wv, Wp, Wqb, Wkb, Wvb, Wpb, Cn * Cn);

  gemm_qkv_fused_kernel<<<dim3(48, 32), dim3(256), 0, stream>>>(
      Xbf, Wqb, Wkb, Wvb, bq, bk, bv, Qb, Kb, Vtb);

  attn_kernel<<<dim3(8, Bn * NH), dim3(256), 0, stream>>>(Qb, Kb, Vtb, Otb);

  gemm_proj_kernel<<<dim3(16, 16, 2), dim3(256), 0, stream>>>(Otb, Wpb, bp, out);
}

// Round 6
// 444.229 us; speedup vs baseline: 1.1425x; 1.1064x over previous
//
#include <hip/hip_runtime.h>
#include <stdint.h>

#define DEVI __device__ __forceinline__

typedef __attribute__((ext_vector_type(8))) short short8;
typedef __attribute__((ext_vector_type(4))) float f32x4;
typedef __attribute__((ext_vector_type(4))) unsigned int u32x4;

static constexpr int Bn = 2;
static constexpr int Tn = 2048;
static constexpr int Cn = 2048;
static constexpr int NH = 16;
static constexpr int HD = 128;
static constexpr int Kdim = 2048;

DEVI unsigned short f2bf(float f) {
  union { float f; unsigned u; } v; v.f = f;
  return (unsigned short)((v.u + 0x7FFFu + ((v.u >> 16) & 1u)) >> 16);
}

DEVI void gload_lds16(const void* g, void* l) {
  __builtin_amdgcn_global_load_lds(
      (const __attribute__((address_space(1))) void*)g,
      (__attribute__((address_space(3))) void*)l, 16, 0, 0);
}

// ---------------- cast fp32 -> bf16 (RNE) ----------------
__global__ __launch_bounds__(256) void cast_bf16_kernel(
    const float* __restrict__ src, unsigned short* __restrict__ dst, int n) {
  int idx = (blockIdx.x * blockDim.x + threadIdx.x) * 4;
  const int stride = gridDim.x * blockDim.x * 4;
  for (; idx < n; idx += stride) {
    f32x4 f = *(const f32x4*)(src + idx);
    unsigned short o[4];
    o[0] = f2bf(f[0]); o[1] = f2bf(f[1]); o[2] = f2bf(f[2]); o[3] = f2bf(f[3]);
    *(unsigned long long*)(dst + idx) = *(const unsigned long long*)o;
  }
}

// one dispatch for all 4 weight matrices (blockIdx.y selects)
__global__ __launch_bounds__(256) void cast4_kernel(
    const float* __restrict__ s0, const float* __restrict__ s1,
    const float* __restrict__ s2, const float* __restrict__ s3,
    unsigned short* __restrict__ d0, unsigned short* __restrict__ d1,
    unsigned short* __restrict__ d2, unsigned short* __restrict__ d3, int n) {
  const int w = blockIdx.y;
  const float* src = (w == 0) ? s0 : (w == 1) ? s1 : (w == 2) ? s2 : s3;
  unsigned short* dst = (w == 0) ? d0 : (w == 1) ? d1 : (w == 2) ? d2 : d3;
  int idx = (blockIdx.x * blockDim.x + threadIdx.x) * 4;
  const int stride = gridDim.x * blockDim.x * 4;
  for (; idx < n; idx += stride) {
    f32x4 f = *(const f32x4*)(src + idx);
    unsigned short o[4];
    o[0] = f2bf(f[0]); o[1] = f2bf(f[1]); o[2] = f2bf(f[2]); o[3] = f2bf(f[3]);
    *(unsigned long long*)(dst + idx) = *(const unsigned long long*)o;
  }
}

// ---------------- fused QKV projection GEMM ----------------
// grid (48, 32), x = n-panel (fastest). BK=32 (r3 footprint: 16 KB LDS,
// ~88 VGPR, 5 blocks/CU) + lane-constant XOR slot swizzle
// (phys chunk = logical chunk ^ ((row>>1)&3)) -> conflict-free ds_read_b128
// in the 16-lane phase model, at zero VALU cost.
// Q/K out: (B,H,T,D) bf16 scattered; V out: (B,H,D,T) bf16 (pre-transposed).
__global__ __launch_bounds__(256) void gemm_qkv_fused_kernel(
    const unsigned short* __restrict__ X,
    const unsigned short* __restrict__ Wq_, const unsigned short* __restrict__ Wk_,
    const unsigned short* __restrict__ Wv_,
    const float* __restrict__ bq_, const float* __restrict__ bk_, const float* __restrict__ bv_,
    unsigned short* __restrict__ Qo, unsigned short* __restrict__ Ko,
    unsigned short* __restrict__ Vo) {
  __shared__ unsigned short As[128 * 32];
  __shared__ unsigned short Bs[128 * 32];
  const int tid = threadIdx.x;
  const int wave = tid >> 6, lane = tid & 63;
  const int wm = wave >> 1, wn = wave & 1;
  const int quad = lane >> 4, lr = lane & 15;

  const int nidx = blockIdx.x;                 // 0..47
  const int m0 = blockIdx.y * 128;
  const int sel = nidx >> 4;
  const int n0 = (nidx & 15) * 128;
  const unsigned short* W = (sel == 0) ? Wq_ : (sel == 1) ? Wk_ : Wv_;
  const float* bias = (sel == 0) ? bq_ : (sel == 1) ? bk_ : bv_;

  f32x4 acc[4][4];
  const f32x4 zero4 = {0.f, 0.f, 0.f, 0.f};
#pragma unroll
  for (int i = 0; i < 4; ++i)
#pragma unroll
    for (int j = 0; j < 4; ++j) acc[i][j] = zero4;

  const int srow = tid >> 2;                               // 0..63
  const int scol = (((tid & 3) ^ ((srow >> 1) & 3)) * 8);  // swizzled k-chunk
  const unsigned short* Ag = X + (size_t)(m0 + srow) * Kdim + scol;
  const unsigned short* Bg = W + (size_t)(n0 + srow) * Kdim + scol;
  unsigned short* Al = &As[tid * 8];
  unsigned short* Bl = &Bs[tid * 8];
  const int fsw = (quad ^ ((lr >> 1) & 3)) * 8;            // reader swizzle

  for (int k0 = 0; k0 < Kdim; k0 += 32) {
    gload_lds16(Ag + k0, Al);
    gload_lds16(Ag + (size_t)64 * Kdim + k0, Al + 2048);
    gload_lds16(Bg + k0, Bl);
    gload_lds16(Bg + (size_t)64 * Kdim + k0, Bl + 2048);
    __syncthreads();
    short8 af[4], bf[4];
#pragma unroll
    for (int mi = 0; mi < 4; ++mi)
      af[mi] = *(const short8*)&As[(wm * 64 + mi * 16 + lr) * 32 + fsw];
#pragma unroll
    for (int ni = 0; ni < 4; ++ni)
      bf[ni] = *(const short8*)&Bs[(wn * 64 + ni * 16 + lr) * 32 + fsw];
#pragma unroll
    for (int mi = 0; mi < 4; ++mi)
#pragma unroll
      for (int ni = 0; ni < 4; ++ni)
        acc[mi][ni] = __builtin_amdgcn_mfma_f32_16x16x32_bf16(af[mi], bf[ni], acc[mi][ni], 0, 0, 0);
    __syncthreads();
  }

  if (sel == 2) {
    // V^T: out[(b,h,d,t)]; 4 consecutive m (=t) per acc reg quad -> 8B stores
#pragma unroll
    for (int ni = 0; ni < 4; ++ni) {
      const int n = n0 + wn * 64 + ni * 16 + lr;
      const float bv = bias[n];
      const int h = n >> 7, d = n & 127;
#pragma unroll
      for (int mi = 0; mi < 4; ++mi) {
        const int m = m0 + wm * 64 + mi * 16 + quad * 4;
        const int b = m >> 11, t = m & 2047;
        unsigned short o4[4];
#pragma unroll
        for (int r = 0; r < 4; ++r) o4[r] = f2bf(acc[mi][ni][r] + bv);
        *(unsigned long long*)&Vo[(((size_t)(b * NH + h)) * HD + d) * Tn + t] =
            *(const unsigned long long*)o4;
      }
    }
  } else {
    unsigned short* Out = (sel == 0) ? Qo : Ko;
#pragma unroll
    for (int ni = 0; ni < 4; ++ni) {
      const int n = n0 + wn * 64 + ni * 16 + lr;
      const float bv = bias[n];
      const int h = n >> 7, d = n & 127;
#pragma unroll
      for (int mi = 0; mi < 4; ++mi) {
#pragma unroll
        for (int r = 0; r < 4; ++r) {
          const int m = m0 + wm * 64 + mi * 16 + quad * 4 + r;
          const int b = m >> 11, t = m & 2047;
          Out[(((size_t)(b * NH + h)) * Tn + t) * HD + d] = f2bf(acc[mi][ni][r] + bv);
        }
      }
    }
  }
}

// ---------------- output projection GEMM (fp32 out) ----------------
// grid (16, 16, 2): x = n (fastest), y = m, z = batch. BK=32 + XOR swizzle.
__global__ __launch_bounds__(256) void gemm_proj_kernel(
    const unsigned short* __restrict__ Aall,  // (B, 2048, 2048) = O^T rows (h*128+d), cols t
    const unsigned short* __restrict__ W,     // Wp (N=C, K) bf16
    const float* __restrict__ bias,
    float* __restrict__ Y) {                  // (B, T, C) fp32
  __shared__ unsigned short As[128 * 32];
  __shared__ unsigned short Bs[128 * 32];
  const int tid = threadIdx.x;
  const int wave = tid >> 6, lane = tid & 63;
  const int wm = wave >> 1, wn = wave & 1;
  const int quad = lane >> 4, lr = lane & 15;

  const int m0 = blockIdx.y * 128, n0 = blockIdx.x * 128;
  const int bz = blockIdx.z;
  const unsigned short* A = Aall + (size_t)bz * Cn * Tn;

  f32x4 acc[4][4];
  const f32x4 zero4 = {0.f, 0.f, 0.f, 0.f};
#pragma unroll
  for (int i = 0; i < 4; ++i)
#pragma unroll
    for (int j = 0; j < 4; ++j) acc[i][j] = zero4;

  const int srow = tid >> 2;
  const int scol = (((tid & 3) ^ ((srow >> 1) & 3)) * 8);
  const unsigned short* Ag = A + (size_t)(m0 + srow) * Kdim + scol;
  const unsigned short* Bg = W + (size_t)(n0 + srow) * Kdim + scol;
  unsigned short* Al = &As[tid * 8];
  unsigned short* Bl = &Bs[tid * 8];
  const int fsw = (quad ^ ((lr >> 1) & 3)) * 8;

  for (int k0 = 0; k0 < Kdim; k0 += 32) {
    gload_lds16(Ag + k0, Al);
    gload_lds16(Ag + (size_t)64 * Kdim + k0, Al + 2048);
    gload_lds16(Bg + k0, Bl);
    gload_lds16(Bg + (size_t)64 * Kdim + k0, Bl + 2048);
    __syncthreads();
    short8 af[4], bf[4];
#pragma unroll
    for (int mi = 0; mi < 4; ++mi)
      af[mi] = *(const short8*)&As[(wm * 64 + mi * 16 + lr) * 32 + fsw];
#pragma unroll
    for (int ni = 0; ni < 4; ++ni)
      bf[ni] = *(const short8*)&Bs[(wn * 64 + ni * 16 + lr) * 32 + fsw];
#pragma unroll
    for (int mi = 0; mi < 4; ++mi)
#pragma unroll
      for (int ni = 0; ni < 4; ++ni)
        acc[mi][ni] = __builtin_amdgcn_mfma_f32_16x16x32_bf16(af[mi], bf[ni], acc[mi][ni], 0, 0, 0);
    __syncthreads();
  }

#pragma unroll
  for (int ni = 0; ni < 4; ++ni) {
    const int n = n0 + wn * 64 + ni * 16 + lr;
    const float bv = bias[n];
#pragma unroll
    for (int mi = 0; mi < 4; ++mi) {
#pragma unroll
      for (int r = 0; r < 4; ++r) {
        const int m = m0 + wm * 64 + mi * 16 + quad * 4 + r;
        Y[((size_t)bz * Tn + m) * Cn + n] = acc[mi][ni][r] + bv;
      }
    }
  }
}

// ---------------- flash attention (fixed-max softmax, paired q-tiles) ---
// Q,K: (BH, T, HD) bf16; V: (BH, HD, T) bf16 (written transposed by QKV).
// Output: O^T (B, H*HD, T) bf16 directly (epilogue transposes via Ps LDS).
__global__ __launch_bounds__(256, 1) void attn_kernel(
    const unsigned short* __restrict__ Q,
    const unsigned short* __restrict__ K,
    const unsigned short* __restrict__ V,
    unsigned short* __restrict__ Ot) {
  constexpr int KST = 136;
  constexpr int VST = 136;   // 144 x 136 (rows 128..143 = ones)
  constexpr int PST = 136;   // 128 x 136 (4 waves x 32 rows)
  __shared__ unsigned short Ks[128 * KST];
  __shared__ unsigned short Vs[144 * VST];
  __shared__ unsigned short Ps[128 * PST];

  const int tid = threadIdx.x;
  const int wave = tid >> 6, lane = tid & 63;
  const int quad = lane >> 4, lr = lane & 15;
  const int bh = blockIdx.y;
  const float SL = 0.08838834764831845f * 1.4426950408889634f;  // scale*log2(e)

  const unsigned short* Kp = K + (size_t)bh * Tn * HD;
  const unsigned short* Vp = V + (size_t)bh * HD * Tn;
  unsigned short* Pw = &Ps[wave * 32 * PST];

  for (int i = tid; i < 16 * VST; i += 256) Vs[128 * VST + i] = 0x3F80;

  const f32x4 zero4 = {0.f, 0.f, 0.f, 0.f};
#pragma unroll 1
  for (int half = 0; half < 2; ++half) {
    const int jt = half ? (15 - (int)blockIdx.x) : (int)blockIdx.x;
    const int q0 = jt * 128;

    const unsigned short* Qp = Q + ((size_t)bh * Tn + q0 + wave * 32) * HD;
    short8 qf[2][4];
#pragma unroll
    for (int mi = 0; mi < 2; ++mi)
#pragma unroll
      for (int ks = 0; ks < 4; ++ks)
        qf[mi][ks] = *(const short8*)&Qp[(mi * 16 + lr) * HD + ks * 32 + quad * 8];

    f32x4 oacc[2][9];
#pragma unroll
    for (int mi = 0; mi < 2; ++mi)
#pragma unroll
      for (int nd = 0; nd < 9; ++nd) oacc[mi][nd] = zero4;

    const int nch = q0 / 128 + 1;
    for (int c = 0; c < nch; ++c) {
      const int k0 = c * 128;
      {
        const int r = tid >> 1;
        const int cc = (tid & 1) * 64;
        const unsigned short* kg = &Kp[(size_t)(k0 + r) * HD + cc];
        const unsigned short* vg = &Vp[(size_t)r * Tn + k0 + cc];
        unsigned short* kl = &Ks[r * KST + cc];
        unsigned short* vl = &Vs[r * VST + cc];
#pragma unroll
        for (int p = 0; p < 8; ++p) {
          *(u32x4*)(kl + p * 8) = *(const u32x4*)(kg + p * 8);
          *(u32x4*)(vl + p * 8) = *(const u32x4*)(vg + p * 8);
        }
      }
      __syncthreads();

      f32x4 sa[2][8];
#pragma unroll
      for (int mi = 0; mi < 2; ++mi)
#pragma unroll
        for (int nt = 0; nt < 8; ++nt) sa[mi][nt] = zero4;
#pragma unroll
      for (int nt = 0; nt < 8; ++nt) {
        short8 kf[4];
#pragma unroll
        for (int ks = 0; ks < 4; ++ks)
          kf[ks] = *(const short8*)&Ks[(nt * 16 + lr) * KST + ks * 32 + quad * 8];
#pragma unroll
        for (int mi = 0; mi < 2; ++mi)
#pragma unroll
          for (int ks = 0; ks < 4; ++ks)
            sa[mi][nt] = __builtin_amdgcn_mfma_f32_16x16x32_bf16(qf[mi][ks], kf[ks], sa[mi][nt], 0, 0, 0);
      }

      if (k0 == q0) {
#pragma unroll
        for (int mi = 0; mi < 2; ++mi)
#pragma unroll
          for (int nt = 0; nt < 8; ++nt)
#pragma unroll
            for (int r = 0; r < 4; ++r) {
              const int qg = q0 + wave * 32 + mi * 16 + quad * 4 + r;
              const int kg = k0 + nt * 16 + lr;
              if (kg > qg) sa[mi][nt][r] = -3.0e38f;
            }
      }

#pragma unroll
      for (int mi = 0; mi < 2; ++mi)
#pragma unroll
        for (int nt = 0; nt < 8; ++nt)
#pragma unroll
          for (int r = 0; r < 4; ++r) {
            const float p = __builtin_amdgcn_exp2f(sa[mi][nt][r] * SL);
            Pw[(mi * 16 + quad * 4 + r) * PST + nt * 16 + lr] = f2bf(p);
          }

#pragma unroll
      for (int kt = 0; kt < 4; ++kt) {
        short8 pf[2];
#pragma unroll
        for (int mi = 0; mi < 2; ++mi)
          pf[mi] = *(const short8*)&Pw[(mi * 16 + lr) * PST + kt * 32 + quad * 8];
#pragma unroll
        for (int nd = 0; nd < 9; ++nd) {
          short8 vf = *(const short8*)&Vs[(nd * 16 + lr) * VST + kt * 32 + quad * 8];
#pragma unroll
          for (int mi = 0; mi < 2; ++mi)
            oacc[mi][nd] = __builtin_amdgcn_mfma_f32_16x16x32_bf16(pf[mi], vf, oacc[mi][nd], 0, 0, 0);
        }
      }
      __syncthreads();
    }

    // epilogue: normalize, stage into Ps (t-major), write O^T coalesced
#pragma unroll
    for (int mi = 0; mi < 2; ++mi)
#pragma unroll
      for (int r = 0; r < 4; ++r) {
        const float rl = 1.0f / oacc[mi][8][r];
        const int tl = wave * 32 + mi * 16 + quad * 4 + r;
#pragma unroll
        for (int nd = 0; nd < 8; ++nd)
          Ps[tl * PST + nd * 16 + lr] = f2bf(oacc[mi][nd][r] * rl);
      }
    __syncthreads();
    {
      unsigned short* Od = Ot + (size_t)bh * HD * Tn + q0;  // row = d, stride Tn
#pragma unroll
      for (int p = 0; p < 8; ++p) {
        const int d = p * 16 + (tid >> 4);
        const int t8 = (tid & 15) * 8;
        alignas(16) unsigned short v[8];
#pragma unroll
        for (int j = 0; j < 8; ++j) v[j] = Ps[(t8 + j) * PST + d];
        *(u32x4*)&Od[(size_t)d * Tn + t8] = *(const u32x4*)v;
      }
    }
    __syncthreads();
  }
}

extern "C" void kernel_launch(void* const* d_in, const int* in_sizes, int n_in,
                              void* d_out, int out_size, void* d_ws, size_t ws_size,
                              hipStream_t stream) {
  const float* x  = (const float*)d_in[0];
  const float* Wq = (const float*)d_in[1];
  const float* bq = (const float*)d_in[2];
  const float* Wk = (const float*)d_in[3];
  const float* bk = (const float*)d_in[4];
  const float* Wv = (const float*)d_in[5];
  const float* bv = (const float*)d_in[6];
  const float* Wp = (const float*)d_in[7];
  const float* bp = (const float*)d_in[8];
  float* out = (float*)d_out;

  char* ws = (char*)d_ws;
  const size_t MB = 1ull << 20;
  unsigned short* Xbf = (unsigned short*)(ws);             // 16MB
  unsigned short* Wqb = (unsigned short*)(ws + 16 * MB);   // 8MB each
  unsigned short* Wkb = (unsigned short*)(ws + 24 * MB);
  unsigned short* Wvb = (unsigned short*)(ws + 32 * MB);
  unsigned short* Wpb = (unsigned short*)(ws + 40 * MB);
  unsigned short* Qb  = (unsigned short*)(ws + 48 * MB);   // 16MB
  unsigned short* Kb  = (unsigned short*)(ws + 64 * MB);   // 16MB
  unsigned short* Vtb = (unsigned short*)(ws + 80 * MB);   // 16MB (B,H,D,T)
  unsigned short* Otb = (unsigned short*)(ws + 96 * MB);   // 16MB (B,H*D,T)

  cast_bf16_kernel<<<dim3(1024), dim3(256), 0, stream>>>(x, Xbf, Bn * Tn * Cn);
  cast4_kernel<<<dim3(512, 4), dim3(256), 0, stream>>>(
      Wq, Wk, Wv, Wp, Wqb, Wkb, Wvb, Wpb, Cn * Cn);

  gemm_qkv_fused_kernel<<<dim3(48, 32), dim3(256), 0, stream>>>(
      Xbf, Wqb, Wkb, Wvb, bq, bk, bv, Qb, Kb, Vtb);

  attn_kernel<<<dim3(8, Bn * NH), dim3(256), 0, stream>>>(Qb, Kb, Vtb, Otb);

  gemm_proj_kernel<<<dim3(16, 16, 2), dim3(256), 0, stream>>>(Otb, Wpb, bp, out);
}